// Round 13
// baseline (192.908 us; speedup 1.0000x reference)
//
#include <hip/hip_runtime.h>
#include <math.h>

#define NN 40000
#define NE 640000
#define D 128
#define NH 4
#define NC 32
#define NEG 0.2f

typedef __attribute__((ext_vector_type(8))) short bf16x8;
typedef __attribute__((ext_vector_type(4))) float f32x4;

__device__ __forceinline__ unsigned pack_bf16(float a, float b) {
  unsigned ua = __float_as_uint(a), ub = __float_as_uint(b);
  ua = (ua + 0x7FFFu + ((ua >> 16) & 1u)) >> 16;
  ub = (ub + 0x7FFFu + ((ub >> 16) & 1u)) & 0xFFFF0000u;
  return ub | ua;
}

__device__ __forceinline__ bf16x8 to_bf16x8(float4 a, float4 b) {
  union { bf16x8 v; unsigned u[4]; } r;
  r.u[0] = pack_bf16(a.x, a.y);
  r.u[1] = pack_bf16(a.z, a.w);
  r.u[2] = pack_bf16(b.x, b.y);
  r.u[3] = pack_bf16(b.z, b.w);
  return r.v;
}

__device__ __forceinline__ float4 f4add(float4 a, float4 b) {
  return make_float4(a.x + b.x, a.y + b.y, a.z + b.z, a.w + b.w);
}

// ====== single fused kernel (3134 blocks):
//   b < 3125, b%5==0  : MFMA xv (625 blocks) — self-contained: weff recomputed
//                       in LDS, B-fragments packed inline from fp32 Wv.
//   b < 3125, b%5!=0  : scatter (2500 blocks, 1 edge/thread, padded CSR
//                       stride 64; self-loops synthesized in gather).
//   b >= 3125         : 9 table blocks -> a_et (tb=0), ev rows (tb=1..8);
//                       consumed only by k_gather.
// counts zeroed beforehand via hipMemsetAsync. ======
__global__ __launch_bounds__(256) void k_sxi(
    const int* __restrict__ ei, const int* __restrict__ etype,
    int* __restrict__ counts, unsigned* __restrict__ packed,
    const float* __restrict__ x, const int* __restrict__ node_type,
    const float* __restrict__ nemb, const float* __restrict__ eemb,
    const float* __restrict__ Wq, const float* __restrict__ Wk,
    const float* __restrict__ Wv,
    const float* __restrict__ att_i, const float* __restrict__ att_j,
    float* __restrict__ ev, float* __restrict__ a_et,
    unsigned* __restrict__ xvh, float* __restrict__ aq, float* __restrict__ ak) {
  __shared__ float sm[1024];
  int b = blockIdx.x, t = threadIdx.x;
  if (b >= 3125) {
    int tb = b - 3125;
    if (tb == 0) {
      // wk_eff rows in LDS -> a_et[ty][h]
      for (int j = t; j < 512; j += 256) {
        int h = j >> 7, d = j & 127;
        float s = 0.f;
#pragma unroll
        for (int c = 0; c < NC; ++c) s = fmaf(att_j[h * NC + c], Wk[(h * NC + c) * D + d], s);
        sm[j] = s;
      }
      __syncthreads();
      if (t < 32) {
        int ty = t >> 2, hh = t & 3;
        float s = 0.f;
#pragma unroll 8
        for (int d = 0; d < D; ++d) s = fmaf(sm[hh * D + d], eemb[ty * D + d], s);
        a_et[t] = s;
      }
    } else {
      int ty = tb - 1;
      if (t < 128) sm[t] = eemb[ty * D + t];
      __syncthreads();
      if (t < 128) {
        const float4* __restrict__ wr = (const float4*)(Wv + (size_t)t * D);
        const float4* __restrict__ er = (const float4*)sm;
        float s = 0.f;
#pragma unroll
        for (int k = 0; k < 32; ++k) {
          float4 ww = wr[k], ee = er[k];
          s = fmaf(ww.x, ee.x, s); s = fmaf(ww.y, ee.y, s);
          s = fmaf(ww.z, ee.z, s); s = fmaf(ww.w, ee.w, s);
        }
        ev[ty * D + t] = s;
      }
    }
    return;
  }
  if (b % 5 != 0) {
    // ---- scatter: 1 edge/thread (R11-verified) ----
    int sb = b - b / 5 - 1;    // 0..2499
    int i = sb * 256 + t;      // covers [0, 640000) exactly
    int src = ei[i];
    int dst = ei[NE + i];
    int et  = etype[i];
    int r = atomicAdd(&counts[dst], 1);
    if (r < 63) packed[(dst << 6) + r] = (unsigned)src | ((unsigned)et << 16);
    return;
  }
  // ---- MFMA xv: weff in LDS (recomputed per block), B inline-packed from Wv ----
  for (int j = t; j < 1024; j += 256) {
    int isq = (j < 512);
    int h = (j >> 7) & 3, d = j & 127;
    const float* __restrict__ Wm = isq ? Wq : Wk;
    const float* __restrict__ am = isq ? att_i : att_j;
    float s = 0.f;
#pragma unroll
    for (int c = 0; c < NC; ++c) s = fmaf(am[h * NC + c], Wm[(h * NC + c) * D + d], s);
    sm[j] = s;
  }
  __syncthreads();
  int bb = b / 5;  // 0..624
  int w = t >> 6, l = t & 63;
  int quad = l >> 4, col = l & 15;
  int n0w = bb * 64 + w * 16;  // 40000 = 625*64
  int node = n0w + col;
  int ntA = node_type[node];
  const float4* __restrict__ xr = (const float4*)(x + (size_t)node * D);
  const float4* __restrict__ nr = (const float4*)(nemb + (size_t)ntA * D);
  bf16x8 afr[4];
#pragma unroll
  for (int s = 0; s < 4; ++s) {
    const float4* p = xr + s * 8 + quad * 2;
    const float4* q4 = nr + s * 8 + quad * 2;
    afr[s] = to_bf16x8(f4add(p[0], q4[0]), f4add(p[1], q4[1]));
  }
  f32x4 acc[9];
#pragma unroll
  for (int ct = 0; ct < 9; ++ct) acc[ct] = (f32x4){0.f, 0.f, 0.f, 0.f};
#pragma unroll
  for (int ct = 0; ct < 8; ++ct) {
    const float* __restrict__ brow = Wv + (size_t)(ct * 16 + col) * D;
#pragma unroll
    for (int s = 0; s < 4; ++s) {
      const float4* wp = (const float4*)(brow + s * 32 + quad * 8);
      bf16x8 bfr = to_bf16x8(wp[0], wp[1]);
      acc[ct] = __builtin_amdgcn_mfma_f32_16x16x32_bf16(afr[s], bfr, acc[ct], 0, 0, 0);
    }
  }
  {  // tile 8: weff rows 0..7 (LDS), rows 8..15 zero
#pragma unroll
    for (int s = 0; s < 4; ++s) {
      bf16x8 bfr;
      if (col < 8) {
        const float4* wp = (const float4*)&sm[col * D + s * 32 + quad * 8];
        bfr = to_bf16x8(wp[0], wp[1]);
      } else {
        union { bf16x8 v; unsigned u[4]; } z; z.u[0] = z.u[1] = z.u[2] = z.u[3] = 0;
        bfr = z.v;
      }
      acc[8] = __builtin_amdgcn_mfma_f32_16x16x32_bf16(afr[s], bfr, acc[8], 0, 0, 0);
    }
  }
  int nodes[4];
#pragma unroll
  for (int r = 0; r < 4; ++r) nodes[r] = n0w + quad * 4 + r;
#pragma unroll
  for (int ct = 0; ct < 8; ++ct) {
#pragma unroll
    for (int r = 0; r < 4; ++r) {
      float val = acc[ct][r];
      float pv = __shfl_xor(val, 1);
      if (!(col & 1)) {
        xvh[nodes[r] * 64 + ct * 8 + (col >> 1)] = pack_bf16(val, pv);
      }
    }
  }
  if (col < 4) {
#pragma unroll
    for (int r = 0; r < 4; ++r) aq[nodes[r] * NH + col] = acc[8][r];
  } else if (col < 8) {
#pragma unroll
    for (int r = 0; r < 4; ++r) ak[nodes[r] * NH + (col - 4)] = acc[8][r];
  }
}

// ---------------- gather: 8-way edge split + per-type ps accumulators ----
// row n: deg = min(counts[n],63) stored edges + 1 virtual self-loop (rec=n, et=0).
__global__ __launch_bounds__(256) void k_gather(const int* __restrict__ counts,
        const unsigned* __restrict__ packed,
        const float* __restrict__ aq, const float* __restrict__ ak,
        const float* __restrict__ a_et, const unsigned* __restrict__ xvh,
        const float* __restrict__ ev, const float* __restrict__ bias,
        float* __restrict__ out) {
  int n = (int)((blockIdx.x * blockDim.x + threadIdx.x) >> 6);
  int l = threadIdx.x & 63;
  if (n >= NN) return;
  int g = l >> 3, q = l & 7;
  int h = q >> 1;
  float aqh = aq[n * NH + h];
  int e0 = n << 6;
  int deg = min(counts[n], 63);
  int m = deg + 1;  // + virtual self-loop at item index deg
  const uint4* __restrict__ xv4 = (const uint4*)xvh;  // row = 16 uint4
  float acc[16];
#pragma unroll
  for (int k = 0; k < 16; ++k) acc[k] = 0.f;
  float ps[8];
#pragma unroll
  for (int k = 0; k < 8; ++k) ps[k] = 0.f;
  int iters = (m + 7) >> 3;
  int i = g;
  bool val = (i < m);
  unsigned rec = (val && i < deg) ? packed[e0 + i] : (unsigned)n;
  int src = (int)(rec & 0xFFFFu), etc = (int)(rec >> 16);
  float sA = ak[src * NH + h] + a_et[etc * NH + h];
  uint4 vb0 = xv4[src * 16 + 2 * q];
  uint4 vb1 = xv4[src * 16 + 2 * q + 1];
  for (int it = 0; it < iters; ++it) {
    int i2 = i + 8;
    bool v2 = (i2 < m);
    float sAn = 0.f; int etn = 0;
    uint4 vb0n = make_uint4(0, 0, 0, 0), vb1n = make_uint4(0, 0, 0, 0);
    if (it + 1 < iters) {
      unsigned rec2 = (v2 && i2 < deg) ? packed[e0 + i2] : (unsigned)n;
      int s2 = (int)(rec2 & 0xFFFFu);
      etn = (int)(rec2 >> 16);
      sAn = ak[s2 * NH + h] + a_et[etn * NH + h];
      vb0n = xv4[s2 * 16 + 2 * q];
      vb1n = xv4[s2 * 16 + 2 * q + 1];
    }
    float s = aqh + sA;
    s = (s > 0.f) ? s : NEG * s;
    float p = val ? __expf(s) : 0.f;
#pragma unroll
    for (int tt = 0; tt < 8; ++tt) ps[tt] += (etc == tt) ? p : 0.f;
    float f[16];
    f[0]  = __uint_as_float(vb0.x << 16); f[1]  = __uint_as_float(vb0.x & 0xFFFF0000u);
    f[2]  = __uint_as_float(vb0.y << 16); f[3]  = __uint_as_float(vb0.y & 0xFFFF0000u);
    f[4]  = __uint_as_float(vb0.z << 16); f[5]  = __uint_as_float(vb0.z & 0xFFFF0000u);
    f[6]  = __uint_as_float(vb0.w << 16); f[7]  = __uint_as_float(vb0.w & 0xFFFF0000u);
    f[8]  = __uint_as_float(vb1.x << 16); f[9]  = __uint_as_float(vb1.x & 0xFFFF0000u);
    f[10] = __uint_as_float(vb1.y << 16); f[11] = __uint_as_float(vb1.y & 0xFFFF0000u);
    f[12] = __uint_as_float(vb1.z << 16); f[13] = __uint_as_float(vb1.z & 0xFFFF0000u);
    f[14] = __uint_as_float(vb1.w << 16); f[15] = __uint_as_float(vb1.w & 0xFFFF0000u);
#pragma unroll
    for (int k = 0; k < 16; ++k) acc[k] = fmaf(p, f[k], acc[k]);
    i = i2; val = v2; sA = sAn; etc = etn; vb0 = vb0n; vb1 = vb1n;
  }
#pragma unroll
  for (int tt = 0; tt < 8; ++tt) {
    ps[tt] += __shfl_xor(ps[tt], 8);
    ps[tt] += __shfl_xor(ps[tt], 16);
    ps[tt] += __shfl_xor(ps[tt], 32);
  }
  float dsum = ((ps[0] + ps[1]) + (ps[2] + ps[3])) + ((ps[4] + ps[5]) + (ps[6] + ps[7]));
  float psg = ps[0];
#pragma unroll
  for (int tt = 1; tt < 8; ++tt) psg = (g == tt) ? ps[tt] : psg;
  const float4* __restrict__ ep = (const float4*)(ev + g * D + 16 * q);
  float4 ea0 = ep[0], ea1 = ep[1], ea2 = ep[2], ea3 = ep[3];
  acc[0]  = fmaf(psg, ea0.x, acc[0]);
  acc[1]  = fmaf(psg, ea0.y, acc[1]);
  acc[2]  = fmaf(psg, ea0.z, acc[2]);
  acc[3]  = fmaf(psg, ea0.w, acc[3]);
  acc[4]  = fmaf(psg, ea1.x, acc[4]);
  acc[5]  = fmaf(psg, ea1.y, acc[5]);
  acc[6]  = fmaf(psg, ea1.z, acc[6]);
  acc[7]  = fmaf(psg, ea1.w, acc[7]);
  acc[8]  = fmaf(psg, ea2.x, acc[8]);
  acc[9]  = fmaf(psg, ea2.y, acc[9]);
  acc[10] = fmaf(psg, ea2.z, acc[10]);
  acc[11] = fmaf(psg, ea2.w, acc[11]);
  acc[12] = fmaf(psg, ea3.x, acc[12]);
  acc[13] = fmaf(psg, ea3.y, acc[13]);
  acc[14] = fmaf(psg, ea3.z, acc[14]);
  acc[15] = fmaf(psg, ea3.w, acc[15]);
#pragma unroll
  for (int k = 0; k < 16; ++k) {
    acc[k] += __shfl_xor(acc[k], 8);
    acc[k] += __shfl_xor(acc[k], 16);
    acc[k] += __shfl_xor(acc[k], 32);
  }
  if (g == 0) {
    float inv = 1.f / (dsum + 1e-16f);
    const float4* __restrict__ b4 = (const float4*)(bias + 16 * q);
    float4* __restrict__ op = (float4*)(out + (size_t)n * D + 16 * q);
#pragma unroll
    for (int k4 = 0; k4 < 4; ++k4) {
      float4 bb = b4[k4];
      op[k4] = make_float4(acc[4 * k4 + 0] * inv + bb.x,
                           acc[4 * k4 + 1] * inv + bb.y,
                           acc[4 * k4 + 2] * inv + bb.z,
                           acc[4 * k4 + 3] * inv + bb.w);
    }
  }
}

extern "C" void kernel_launch(void* const* d_in, const int* in_sizes, int n_in,
                              void* d_out, int out_size, void* d_ws, size_t ws_size,
                              hipStream_t stream) {
  const float* x      = (const float*)d_in[0];
  const int*   ei     = (const int*)d_in[1];
  const int*   ntype  = (const int*)d_in[2];
  const int*   etype  = (const int*)d_in[3];
  const float* Wq     = (const float*)d_in[4];
  const float* Wk     = (const float*)d_in[5];
  const float* Wv     = (const float*)d_in[6];
  const float* att_i  = (const float*)d_in[7];
  const float* att_j  = (const float*)d_in[8];
  const float* bias   = (const float*)d_in[9];
  const float* nemb   = (const float*)d_in[10];
  const float* eemb   = (const float*)d_in[11];
  float* out = (float*)d_out;

  float* ws      = (float*)d_ws;
  unsigned* xvh  = (unsigned*)ws;               // NN*64 uints (bf16 pairs)
  float* aq      = ws + (size_t)NN * 64;        // NN*4
  float* ak      = aq + NN * NH;                // NN*4
  float* ev      = ak + NN * NH;                // 1024
  float* a_et    = ev + 1024;                   // 32
  int* counts    = (int*)(a_et + 32);           // NN
  unsigned* packed = (unsigned*)(counts + NN);  // NN*64 padded CSR

  hipMemsetAsync(counts, 0, NN * sizeof(int), stream);
  k_sxi<<<dim3(3134), dim3(256), 0, stream>>>(ei, etype, counts, packed,
                                              x, ntype, nemb, eemb,
                                              Wq, Wk, Wv, att_i, att_j,
                                              ev, a_et, xvh, aq, ak);
  k_gather<<<dim3((NN + 3) / 4), dim3(256), 0, stream>>>(counts, packed, aq, ak, a_et,
                                                         xvh, ev, bias, out);
}